// Round 14
// baseline (125.263 us; speedup 1.0000x reference)
//
#include <hip/hip_runtime.h>
#include <cstddef>
#include <math.h>

#define NN 50000
#define DEG 16
#define NEG_SLOPE 0.2f

typedef __attribute__((ext_vector_type(8))) short bf16x8;
typedef __attribute__((ext_vector_type(4))) float f32x4;

__device__ inline unsigned short f2bf(float x) {
    unsigned u = __float_as_uint(x);
    return (unsigned short)((u + 0x7FFF + ((u >> 16) & 1)) >> 16);
}
__device__ inline float bf2f(unsigned short u) {
    return __uint_as_float(((unsigned)u) << 16);
}
__device__ inline unsigned pack_bf2(float lo, float hi) {
    return (unsigned)f2bf(lo) | ((unsigned)f2bf(hi) << 16);
}
__device__ inline void gld_lds16f(const float* g, float* l) {
    __builtin_amdgcn_global_load_lds((const __attribute__((address_space(1))) void*)g,
                                     (__attribute__((address_space(3))) void*)l, 16, 0, 0);
}

// ---------------- prep: W1/Wh transpose -> bf16 ----------------------------------
__global__ void prep_k(const float* __restrict__ W1, unsigned short* __restrict__ Wt1,
                       const float* __restrict__ Wh, unsigned short* __restrict__ Wth)
{
    const int b = blockIdx.x;
    if (b < 128) {                         // Wt1[c][k], 128x256
        int idx = b * 256 + threadIdx.x;
        int c = idx >> 8, k = idx & 255;
        Wt1[idx] = f2bf(W1[(size_t)k * 128 + c]);
    } else {                               // Wth[c][k], 128x128
        int idx = (b - 128) * 256 + threadIdx.x;
        int c = idx >> 7, k = idx & 127;
        Wth[idx] = f2bf(Wh[(size_t)k * 128 + c]);
    }
}

// ---------------- layer-1 MFMA GEMM [N,256](f32 direct) x [256,128] --------------
// SINGLE-SHOT blocks (r14): grid 3125, one 16-row tile per block, no inter-tile
// loop, no double-buffer. Stage DMA issued first; B-regs load under its shadow;
// one barrier; 16 MFMAs; done. Latency hidden by block-level parallelism (the
// structure that measured best in the fused kernels), not intra-block pipelining.
__launch_bounds__(256)
__global__ void gemm1_k(const float* __restrict__ A,
                        const unsigned short* __restrict__ Wt,
                        const float* __restrict__ al, const float* __restrict__ ar,
                        unsigned short* __restrict__ feat,
                        float* __restrict__ el, float* __restrict__ er)
{
    constexpr int K = 256, KS = 8;
    __shared__ __align__(16) float buf[4096];      // 1024 slots x 16B
    const int tid = threadIdx.x;
    const int w = tid >> 6, l = tid & 63;
    const int lr = l & 15, lq = l >> 4;
    const int col0 = w * 32;
    const int t = blockIdx.x;                      // tile = rows t*16..t*16+15
    const int row0 = t * 16;                       // 3125*16 = 50000 exact

    // issue the A-tile stage DMA first (swizzled per-lane source, linear LDS dest)
#pragma unroll
    for (int p = 0; p < 4; p++) {
        int j = tid + p * 256;                     // slot 0..1023
        int row = j >> 6;
        int kg = (j & 63) ^ (row & 7);             // inverse of read-side XOR
        gld_lds16f(A + (size_t)(row0 + row) * 256 + kg * 4, &buf[(size_t)j * 4]);
    }

    // B regs load under the DMA shadow
    bf16x8 B0[KS], B1[KS];
#pragma unroll
    for (int ks = 0; ks < KS; ks++) {
        B0[ks] = *(const bf16x8*)(Wt + (size_t)(col0 + lr) * K + ks * 32 + lq * 8);
        B1[ks] = *(const bf16x8*)(Wt + (size_t)(col0 + 16 + lr) * K + ks * 32 + lq * 8);
    }
    __syncthreads();                               // drains DMA (vmcnt) + B loads

    f32x4 acc0 = {0.f, 0.f, 0.f, 0.f}, acc1 = {0.f, 0.f, 0.f, 0.f};
#pragma unroll
    for (int ks = 0; ks < KS; ks++) {
        const int kg0 = ks * 8 + lq * 2;
        const int s0 = lr * 64 + (kg0 ^ (lr & 7));
        const int s1 = lr * 64 + ((kg0 + 1) ^ (lr & 7));
        float4 va = *(const float4*)&buf[(size_t)s0 * 4];
        float4 vb = *(const float4*)&buf[(size_t)s1 * 4];
        bf16x8 a = {(short)f2bf(va.x), (short)f2bf(va.y),
                    (short)f2bf(va.z), (short)f2bf(va.w),
                    (short)f2bf(vb.x), (short)f2bf(vb.y),
                    (short)f2bf(vb.z), (short)f2bf(vb.w)};
        acc0 = __builtin_amdgcn_mfma_f32_16x16x32_bf16(a, B0[ks], acc0, 0, 0, 0);
        acc1 = __builtin_amdgcn_mfma_f32_16x16x32_bf16(a, B1[ks], acc1, 0, 0, 0);
    }

    // epilogue: feat bf16 store + el/er (head = wave)
#pragma unroll
    for (int reg = 0; reg < 4; reg++) {
        const int r = row0 + lq * 4 + reg;
        feat[(size_t)r * 128 + col0 + lr]      = f2bf(acc0[reg]);
        feat[(size_t)r * 128 + col0 + 16 + lr] = f2bf(acc1[reg]);
    }
    float pe[4], pr[4];
#pragma unroll
    for (int reg = 0; reg < 4; reg++) {
        pe[reg] = acc0[reg] * al[col0 + lr] + acc1[reg] * al[col0 + 16 + lr];
        pr[reg] = acc0[reg] * ar[col0 + lr] + acc1[reg] * ar[col0 + 16 + lr];
    }
#pragma unroll
    for (int m = 1; m < 16; m <<= 1)
#pragma unroll
        for (int reg = 0; reg < 4; reg++) {
            pe[reg] += __shfl_xor(pe[reg], m);
            pr[reg] += __shfl_xor(pr[reg], m);
        }
    if (lr == 0) {
#pragma unroll
        for (int reg = 0; reg < 4; reg++) {
            const int r = row0 + lq * 4 + reg;
            el[r * 4 + w] = pe[reg];
            er[r * 4 + w] = pr[reg];
        }
    }
}

// ---------------- FUSED: agg1 (H=4, relu) + hidden MFMA GEMM ---------------------
// (r11/r13 register-gather version, unchanged)
__launch_bounds__(256)
__global__ void fusedh_k(const unsigned short* __restrict__ feat1,
                         const float* __restrict__ el1, const float* __restrict__ er1,
                         const int* __restrict__ src, const float* __restrict__ b1,
                         const unsigned short* __restrict__ Wt,
                         const float* __restrict__ alh, const float* __restrict__ arh,
                         unsigned short* __restrict__ feat2,
                         float* __restrict__ el, float* __restrict__ er)
{
    __shared__ __align__(16) unsigned short abuf[256 * 8];   // 256 slots x 16B
    __shared__ float s_alpha[16][64];
    __shared__ float redE[4][16], redR[4][16];
    const int tid = threadIdx.x;
    const int w = tid >> 6, lane = tid & 63;
    const int q = lane >> 4, li = lane & 15;
    const int slot = w * 4 + q;
    const int row0 = blockIdx.x * 16;
    const int node = row0 + slot;
    const int col0 = w * 32;

    // ---- phase A: edge softmax (4 heads) ----
    const int s = src[node * DEG + li];
    {
        const float4 elv = *(const float4*)(el1 + (size_t)s * 4);
        const float4 erv = *(const float4*)(er1 + (size_t)node * 4);
        float e[4] = {elv.x + erv.x, elv.y + erv.y, elv.z + erv.z, elv.w + erv.w};
#pragma unroll
        for (int h = 0; h < 4; h++) {
            float x = e[h];
            x = (x > 0.f) ? x : NEG_SLOPE * x;
            float mx = x;
#pragma unroll
            for (int d = 1; d < 16; d <<= 1) mx = fmaxf(mx, __shfl_xor(mx, d, 16));
            float ex = expf(x - mx);
            float den = ex;
#pragma unroll
            for (int d = 1; d < 16; d <<= 1) den += __shfl_xor(den, d, 16);
            s_alpha[slot][h * 16 + li] = ex / den;
        }
    }
    // ---- phase A: gather + accumulate ----
    uint4 v[16];
#pragma unroll
    for (int jj = 0; jj < 16; jj++) {
        int sj = __shfl(s, (lane & 48) | jj);
        v[jj] = *(const uint4*)(feat1 + (size_t)sj * 128 + li * 8);
    }
    float acc[8] = {0.f, 0.f, 0.f, 0.f, 0.f, 0.f, 0.f, 0.f};
    const int hrow = (li >> 2) * 16;
#pragma unroll
    for (int jj = 0; jj < 16; jj++) {
        float a = s_alpha[slot][hrow + jj];
        unsigned u0 = v[jj].x, u1 = v[jj].y, u2 = v[jj].z, u3 = v[jj].w;
        acc[0] += a * bf2f((unsigned short)(u0 & 0xFFFF));
        acc[1] += a * bf2f((unsigned short)(u0 >> 16));
        acc[2] += a * bf2f((unsigned short)(u1 & 0xFFFF));
        acc[3] += a * bf2f((unsigned short)(u1 >> 16));
        acc[4] += a * bf2f((unsigned short)(u2 & 0xFFFF));
        acc[5] += a * bf2f((unsigned short)(u2 >> 16));
        acc[6] += a * bf2f((unsigned short)(u3 & 0xFFFF));
        acc[7] += a * bf2f((unsigned short)(u3 >> 16));
    }
    const float4 bb0 = *(const float4*)(b1 + li * 8);
    const float4 bb1 = *(const float4*)(b1 + li * 8 + 4);
    float o[8];
    o[0] = fmaxf(acc[0] + bb0.x, 0.f); o[1] = fmaxf(acc[1] + bb0.y, 0.f);
    o[2] = fmaxf(acc[2] + bb0.z, 0.f); o[3] = fmaxf(acc[3] + bb0.w, 0.f);
    o[4] = fmaxf(acc[4] + bb1.x, 0.f); o[5] = fmaxf(acc[5] + bb1.y, 0.f);
    o[6] = fmaxf(acc[6] + bb1.z, 0.f); o[7] = fmaxf(acc[7] + bb1.w, 0.f);
    {
        uint4 pk;
        pk.x = pack_bf2(o[0], o[1]);
        pk.y = pack_bf2(o[2], o[3]);
        pk.z = pack_bf2(o[4], o[5]);
        pk.w = pack_bf2(o[6], o[7]);
        int jw = ((li >> 2) * 64 + (li & 3) * 16 + slot) ^ (li & 7);
        *(uint4*)&abuf[(size_t)jw * 8] = pk;
    }

    // B regs (K=128): loaded after the gather phase (peak-VGPR trim)
    bf16x8 B0[4], B1[4];
#pragma unroll
    for (int ks = 0; ks < 4; ks++) {
        B0[ks] = *(const bf16x8*)(Wt + (size_t)(col0 + li) * 128 + ks * 32 + q * 8);
        B1[ks] = *(const bf16x8*)(Wt + (size_t)(col0 + 16 + li) * 128 + ks * 32 + q * 8);
    }
    __syncthreads();

    // ---- phase B: MFMA ----
    f32x4 acc0 = {0.f, 0.f, 0.f, 0.f}, acc1 = {0.f, 0.f, 0.f, 0.f};
#pragma unroll
    for (int ks = 0; ks < 4; ks++) {
        int jr = (ks * 64 + lane) ^ ((ks * 4 + q) & 7);
        bf16x8 a = *(const bf16x8*)&abuf[(size_t)jr * 8];
        acc0 = __builtin_amdgcn_mfma_f32_16x16x32_bf16(a, B0[ks], acc0, 0, 0, 0);
        acc1 = __builtin_amdgcn_mfma_f32_16x16x32_bf16(a, B1[ks], acc1, 0, 0, 0);
    }

    // epilogue: hidden feat bf16 + el/er (1 head, cross-wave reduce)
#pragma unroll
    for (int reg = 0; reg < 4; reg++) {
        const int r = row0 + q * 4 + reg;
        feat2[(size_t)r * 128 + col0 + li]      = f2bf(acc0[reg]);
        feat2[(size_t)r * 128 + col0 + 16 + li] = f2bf(acc1[reg]);
    }
    float pe[4], pr[4];
#pragma unroll
    for (int reg = 0; reg < 4; reg++) {
        pe[reg] = acc0[reg] * alh[col0 + li] + acc1[reg] * alh[col0 + 16 + li];
        pr[reg] = acc0[reg] * arh[col0 + li] + acc1[reg] * arh[col0 + 16 + li];
    }
#pragma unroll
    for (int m = 1; m < 16; m <<= 1)
#pragma unroll
        for (int reg = 0; reg < 4; reg++) {
            pe[reg] += __shfl_xor(pe[reg], m);
            pr[reg] += __shfl_xor(pr[reg], m);
        }
    if (li == 0) {
#pragma unroll
        for (int reg = 0; reg < 4; reg++) {
            redE[w][q * 4 + reg] = pe[reg];
            redR[w][q * 4 + reg] = pr[reg];
        }
    }
    __syncthreads();
    if (tid < 16) {
        el[row0 + tid] = redE[0][tid] + redE[1][tid] + redE[2][tid] + redE[3][tid];
        er[row0 + tid] = redR[0][tid] + redR[1][tid] + redR[2][tid] + redR[3][tid];
    }
}

// ---------------- FUSED: agg2 (H=1, relu) + gemm40 -------------------------------
// (r13 version: W2 staged before phase A)
__launch_bounds__(256)
__global__ void fused40_k(const unsigned short* __restrict__ feat2,
                          const float* __restrict__ elA, const float* __restrict__ erA,
                          const int* __restrict__ src, const float* __restrict__ bh,
                          const float* __restrict__ W2,
                          const float* __restrict__ al2, const float* __restrict__ ar2,
                          unsigned short* __restrict__ f40,
                          float* __restrict__ el2, float* __restrict__ er2)
{
    __shared__ float As[32][132];
    __shared__ float Ws[128 * 40];
    const int tid = threadIdx.x;
    const int w = tid >> 6, lane = tid & 63;
    const int q = lane >> 4, li = lane & 15;
    const int slot = w * 4 + q;
    const int row0 = blockIdx.x * 32;

    {   // stage W2 into LDS first: streamed load latency hides under the gather
        const float4* s4 = (const float4*)W2;
        float4* d4 = (float4*)Ws;
#pragma unroll
        for (int p = 0; p < 5; p++) d4[tid + 256 * p] = s4[tid + 256 * p];
    }

    // ---- phase A: agg for 32 nodes, 2 rounds of 16 ----
#pragma unroll
    for (int rnd = 0; rnd < 2; rnd++) {
        const int row = rnd * 16 + slot;
        int node = row0 + row;
        if (node > NN - 1) node = NN - 1;
        const int s = src[node * DEG + li];
        float x = elA[s] + erA[node];
        x = (x > 0.f) ? x : NEG_SLOPE * x;
        float mx = x;
#pragma unroll
        for (int d = 1; d < 16; d <<= 1) mx = fmaxf(mx, __shfl_xor(mx, d, 16));
        float ex = expf(x - mx);
        float den = ex;
#pragma unroll
        for (int d = 1; d < 16; d <<= 1) den += __shfl_xor(den, d, 16);
        const float alpha = ex / den;

        uint4 v[16];
#pragma unroll
        for (int jj = 0; jj < 16; jj++) {
            int sj = __shfl(s, (lane & 48) | jj);
            v[jj] = *(const uint4*)(feat2 + (size_t)sj * 128 + li * 8);
        }
        float acc[8] = {0.f, 0.f, 0.f, 0.f, 0.f, 0.f, 0.f, 0.f};
#pragma unroll
        for (int jj = 0; jj < 16; jj++) {
            float a = __shfl(alpha, (lane & 48) | jj);
            unsigned u0 = v[jj].x, u1 = v[jj].y, u2 = v[jj].z, u3 = v[jj].w;
            acc[0] += a * bf2f((unsigned short)(u0 & 0xFFFF));
            acc[1] += a * bf2f((unsigned short)(u0 >> 16));
            acc[2] += a * bf2f((unsigned short)(u1 & 0xFFFF));
            acc[3] += a * bf2f((unsigned short)(u1 >> 16));
            acc[4] += a * bf2f((unsigned short)(u2 & 0xFFFF));
            acc[5] += a * bf2f((unsigned short)(u2 >> 16));
            acc[6] += a * bf2f((unsigned short)(u3 & 0xFFFF));
            acc[7] += a * bf2f((unsigned short)(u3 >> 16));
        }
        const float4 bb0 = *(const float4*)(bh + li * 8);
        const float4 bb1 = *(const float4*)(bh + li * 8 + 4);
        float4 o0, o1;
        o0.x = fmaxf(acc[0] + bb0.x, 0.f); o0.y = fmaxf(acc[1] + bb0.y, 0.f);
        o0.z = fmaxf(acc[2] + bb0.z, 0.f); o0.w = fmaxf(acc[3] + bb0.w, 0.f);
        o1.x = fmaxf(acc[4] + bb1.x, 0.f); o1.y = fmaxf(acc[5] + bb1.y, 0.f);
        o1.z = fmaxf(acc[6] + bb1.z, 0.f); o1.w = fmaxf(acc[7] + bb1.w, 0.f);
        *(float4*)&As[row][li * 8]     = o0;
        *(float4*)&As[row][li * 8 + 4] = o1;
    }
    __syncthreads();

    // ---- phase B: gemm40 (32 rows x 40 cols) ----
    const int tx = tid & 31;
    const int ty = tid >> 5;
    const int ctx = (tx < 20) ? tx : 19;
    const float2* Wf2 = (const float2*)Ws;
    float acc[4][2] = {};
#pragma unroll 4
    for (int k = 0; k < 128; k++) {
        float2 wv = Wf2[k * 20 + ctx];
#pragma unroll
        for (int i = 0; i < 4; i++) {
            float a = As[ty * 4 + i][k];
            acc[i][0] += a * wv.x;
            acc[i][1] += a * wv.y;
        }
    }
    float pel[4], per[4];
#pragma unroll
    for (int i = 0; i < 4; i++) {
        float vl = 0.f, vr = 0.f;
        if (tx < 20) {
            vl = acc[i][0] * al2[2 * ctx] + acc[i][1] * al2[2 * ctx + 1];
            vr = acc[i][0] * ar2[2 * ctx] + acc[i][1] * ar2[2 * ctx + 1];
        }
        pel[i] = vl; per[i] = vr;
    }
#pragma unroll
    for (int m = 1; m < 32; m <<= 1) {
#pragma unroll
        for (int i = 0; i < 4; i++) {
            pel[i] += __shfl_xor(pel[i], m);
            per[i] += __shfl_xor(per[i], m);
        }
    }
#pragma unroll
    for (int i = 0; i < 4; i++) {
        int r = row0 + ty * 4 + i;
        if (r < NN) {
            if (tx < 20) *(unsigned*)&f40[(size_t)r * 40 + 2 * tx] = pack_bf2(acc[i][0], acc[i][1]);
            if (tx == 0) { el2[r] = pel[i]; er2[r] = per[i]; }
        }
    }
}

// ---------------- edge softmax + aggregate 40 cols bf16 + log_softmax ------------
__launch_bounds__(256)
__global__ void agg40_ls_k(const unsigned short* __restrict__ feat, const float* __restrict__ el,
                           const float* __restrict__ er, const int* __restrict__ src,
                           const float* __restrict__ bias, float* __restrict__ out)
{
    const int tid = threadIdx.x;
    const int w = tid >> 6, lane = tid & 63;
    const int half = lane >> 5, li = lane & 31;
    const int node = blockIdx.x * 8 + w * 2 + half;

    const int s = src[node * DEG + (li & 15)];
    float e = el[s] + er[node];
    e = (e > 0.f) ? e : NEG_SLOPE * e;
    float mx = e;
#pragma unroll
    for (int d = 1; d < 16; d <<= 1) mx = fmaxf(mx, __shfl_xor(mx, d, 16));
    float ex = expf(e - mx);
    float den = ex;
#pragma unroll
    for (int d = 1; d < 16; d <<= 1) den += __shfl_xor(den, d, 16);
    const float alpha = ex / den;

    const int cli = (li < 20) ? li : 19;
    float acc0 = 0.f, acc1 = 0.f;
#pragma unroll
    for (int jj = 0; jj < DEG; jj++) {
        int sj = __shfl(s, jj, 32);
        float a = __shfl(alpha, jj, 32);
        unsigned v = *(const unsigned*)(feat + (size_t)sj * 40 + 2 * cli);
        acc0 += a * bf2f((unsigned short)(v & 0xFFFF));
        acc1 += a * bf2f((unsigned short)(v >> 16));
    }
    float v0 = acc0 + bias[2 * cli], v1 = acc1 + bias[2 * cli + 1];
    float m2 = (li < 20) ? fmaxf(v0, v1) : -INFINITY;
#pragma unroll
    for (int d = 1; d < 32; d <<= 1) m2 = fmaxf(m2, __shfl_xor(m2, d, 32));
    float pe = (li < 20) ? (expf(v0 - m2) + expf(v1 - m2)) : 0.f;
    float se = pe;
#pragma unroll
    for (int d = 1; d < 32; d <<= 1) se += __shfl_xor(se, d, 32);
    if (li < 20) {
        float ls = m2 + logf(se);
        out[(size_t)node * 40 + 2 * li]     = v0 - ls;
        out[(size_t)node * 40 + 2 * li + 1] = v1 - ls;
    }
}

extern "C" void kernel_launch(void* const* d_in, const int* in_sizes, int n_in,
                              void* d_out, int out_size, void* d_ws, size_t ws_size,
                              hipStream_t stream)
{
    const float* features = (const float*)d_in[0];
    const int*   src      = (const int*)d_in[1];
    // d_in[2] = dst: structurally repeat(arange(N),16) -> unused
    const float* W1  = (const float*)d_in[3];
    const float* al1 = (const float*)d_in[4];
    const float* ar1 = (const float*)d_in[5];
    const float* b1  = (const float*)d_in[6];
    const float* Wh  = (const float*)d_in[7];
    const float* alh = (const float*)d_in[8];
    const float* arh = (const float*)d_in[9];
    const float* bh  = (const float*)d_in[10];
    const float* W2  = (const float*)d_in[11];
    const float* al2 = (const float*)d_in[12];
    const float* ar2 = (const float*)d_in[13];
    const float* b2  = (const float*)d_in[14];
    float* out = (float*)d_out;

    float* ws = (float*)d_ws;
    unsigned short* featb  = (unsigned short*)ws;            // N*128 bf16 layer-1 feat
    unsigned short* featb2 = featb + (size_t)NN * 128;       // N*128 bf16 hidden feat
    float* el1  = (float*)(featb2 + (size_t)NN * 128);       // N*4
    float* er1  = el1 + (size_t)NN * 4;                      // N*4
    float* elA  = er1 + (size_t)NN * 4;                      // N
    float* erA  = elA + NN;                                  // N
    float* el2  = erA + NN;                                  // N
    float* er2  = el2 + NN;                                  // N
    unsigned short* f40b = (unsigned short*)(er2 + NN);      // N*40 bf16
    unsigned short* Wt1  = f40b + (size_t)NN * 40;           // 128*256 bf16
    unsigned short* Wth  = Wt1 + 128 * 256;                  // 128*128 bf16

    dim3 blk(256);
    prep_k<<<192, blk, 0, stream>>>(W1, Wt1, Wh, Wth);
    gemm1_k<<<3125, blk, 0, stream>>>(features, Wt1, al1, ar1, featb, el1, er1);
    fusedh_k<<<3125, blk, 0, stream>>>(featb, el1, er1, src, b1, Wth, alh, arh,
                                       featb2, elA, erA);
    fused40_k<<<1563, blk, 0, stream>>>(featb2, elA, erA, src, bh, W2, al2, ar2,
                                        f40b, el2, er2);
    agg40_ls_k<<<6250, blk, 0, stream>>>(f40b, el2, er2, src, b2, out);
}

// Round 15
// 114.096 us; speedup vs baseline: 1.0979x; 1.0979x over previous
//
#include <hip/hip_runtime.h>
#include <cstddef>
#include <math.h>

#define NN 50000
#define DEG 16
#define NEG_SLOPE 0.2f

typedef __attribute__((ext_vector_type(8))) short bf16x8;
typedef __attribute__((ext_vector_type(4))) float f32x4;

__device__ inline unsigned short f2bf(float x) {
    unsigned u = __float_as_uint(x);
    return (unsigned short)((u + 0x7FFF + ((u >> 16) & 1)) >> 16);
}
__device__ inline float bf2f(unsigned short u) {
    return __uint_as_float(((unsigned)u) << 16);
}
__device__ inline unsigned pack_bf2(float lo, float hi) {
    return (unsigned)f2bf(lo) | ((unsigned)f2bf(hi) << 16);
}
__device__ inline void gld_lds16f(const float* g, float* l) {
    __builtin_amdgcn_global_load_lds((const __attribute__((address_space(1))) void*)g,
                                     (__attribute__((address_space(3))) void*)l, 16, 0, 0);
}

// ---------------- prep: W1/Wh transpose -> bf16; W2t[48][128] zero-padded --------
__global__ void prep_k(const float* __restrict__ W1, unsigned short* __restrict__ Wt1,
                       const float* __restrict__ Wh, unsigned short* __restrict__ Wth,
                       const float* __restrict__ W2, unsigned short* __restrict__ W2t)
{
    const int b = blockIdx.x;
    if (b < 128) {                         // Wt1[c][k], 128x256
        int idx = b * 256 + threadIdx.x;
        int c = idx >> 8, k = idx & 255;
        Wt1[idx] = f2bf(W1[(size_t)k * 128 + c]);
    } else if (b < 192) {                  // Wth[c][k], 128x128
        int idx = (b - 128) * 256 + threadIdx.x;
        int c = idx >> 7, k = idx & 127;
        Wth[idx] = f2bf(Wh[(size_t)k * 128 + c]);
    } else {                               // W2t[c][k], 48x128 (cols 40-47 zero)
        int idx = (b - 192) * 256 + threadIdx.x;
        if (idx < 48 * 128) {
            int c = idx >> 7, k = idx & 127;
            W2t[idx] = (c < 40) ? f2bf(W2[(size_t)k * 40 + c]) : (unsigned short)0;
        }
    }
}

// ---------------- layer-1 tiled MFMA GEMM [N,256](f32 direct) x [256,128] --------
// (r13 version: TPB=2, double-buffered, swizzled global_load_lds staging)
__launch_bounds__(256)
__global__ void gemm1_k(const float* __restrict__ A,
                        const unsigned short* __restrict__ Wt,
                        const float* __restrict__ al, const float* __restrict__ ar,
                        unsigned short* __restrict__ feat,
                        float* __restrict__ el, float* __restrict__ er)
{
    constexpr int K = 256, KS = 8, TPB = 2;
    __shared__ __align__(16) float buf[2][4096];
    const int tid = threadIdx.x;
    const int w = tid >> 6, l = tid & 63;
    const int lr = l & 15, lq = l >> 4;
    const int col0 = w * 32;

    bf16x8 B0[KS], B1[KS];
#pragma unroll
    for (int ks = 0; ks < KS; ks++) {
        B0[ks] = *(const bf16x8*)(Wt + (size_t)(col0 + lr) * K + ks * 32 + lq * 8);
        B1[ks] = *(const bf16x8*)(Wt + (size_t)(col0 + 16 + lr) * K + ks * 32 + lq * 8);
    }

    const int t0 = blockIdx.x * TPB;
    const int tmax = NN / 16;
    const int t1 = (t0 + TPB < tmax) ? t0 + TPB : tmax;
    if (t0 >= tmax) return;

    auto stage = [&](int t, int b) {
#pragma unroll
        for (int p = 0; p < 4; p++) {
            int j = tid + p * 256;
            int row = j >> 6;
            int kg = (j & 63) ^ (row & 7);
            gld_lds16f(A + (size_t)(t * 16 + row) * 256 + kg * 4, &buf[b][(size_t)j * 4]);
        }
    };
    stage(t0, t0 & 1);

    for (int t = t0; t < t1; ++t) {
        __syncthreads();
        if (t + 1 < t1) stage(t + 1, (t + 1) & 1);

        f32x4 acc0 = {0.f, 0.f, 0.f, 0.f}, acc1 = {0.f, 0.f, 0.f, 0.f};
        const float* bb = buf[t & 1];
#pragma unroll
        for (int ks = 0; ks < KS; ks++) {
            const int kg0 = ks * 8 + lq * 2;
            const int s0 = lr * 64 + (kg0 ^ (lr & 7));
            const int s1 = lr * 64 + ((kg0 + 1) ^ (lr & 7));
            float4 va = *(const float4*)&bb[(size_t)s0 * 4];
            float4 vb = *(const float4*)&bb[(size_t)s1 * 4];
            bf16x8 a = {(short)f2bf(va.x), (short)f2bf(va.y),
                        (short)f2bf(va.z), (short)f2bf(va.w),
                        (short)f2bf(vb.x), (short)f2bf(vb.y),
                        (short)f2bf(vb.z), (short)f2bf(vb.w)};
            acc0 = __builtin_amdgcn_mfma_f32_16x16x32_bf16(a, B0[ks], acc0, 0, 0, 0);
            acc1 = __builtin_amdgcn_mfma_f32_16x16x32_bf16(a, B1[ks], acc1, 0, 0, 0);
        }

        const int row0 = t * 16;
#pragma unroll
        for (int reg = 0; reg < 4; reg++) {
            const int r = row0 + lq * 4 + reg;
            feat[(size_t)r * 128 + col0 + lr]      = f2bf(acc0[reg]);
            feat[(size_t)r * 128 + col0 + 16 + lr] = f2bf(acc1[reg]);
        }

        float pe[4], pr[4];
#pragma unroll
        for (int reg = 0; reg < 4; reg++) {
            pe[reg] = acc0[reg] * al[col0 + lr] + acc1[reg] * al[col0 + 16 + lr];
            pr[reg] = acc0[reg] * ar[col0 + lr] + acc1[reg] * ar[col0 + 16 + lr];
        }
#pragma unroll
        for (int m = 1; m < 16; m <<= 1)
#pragma unroll
            for (int reg = 0; reg < 4; reg++) {
                pe[reg] += __shfl_xor(pe[reg], m);
                pr[reg] += __shfl_xor(pr[reg], m);
            }
        if (lr == 0) {
#pragma unroll
            for (int reg = 0; reg < 4; reg++) {
                const int r = row0 + lq * 4 + reg;
                el[r * 4 + w] = pe[reg];
                er[r * 4 + w] = pr[reg];
            }
        }
    }
}

// ---------------- FUSED: agg1 (H=4, relu) + hidden MFMA GEMM ---------------------
// (r11/r13 register-gather version, unchanged)
__launch_bounds__(256)
__global__ void fusedh_k(const unsigned short* __restrict__ feat1,
                         const float* __restrict__ el1, const float* __restrict__ er1,
                         const int* __restrict__ src, const float* __restrict__ b1,
                         const unsigned short* __restrict__ Wt,
                         const float* __restrict__ alh, const float* __restrict__ arh,
                         unsigned short* __restrict__ feat2,
                         float* __restrict__ el, float* __restrict__ er)
{
    __shared__ __align__(16) unsigned short abuf[256 * 8];   // 256 slots x 16B
    __shared__ float s_alpha[16][64];
    __shared__ float redE[4][16], redR[4][16];
    const int tid = threadIdx.x;
    const int w = tid >> 6, lane = tid & 63;
    const int q = lane >> 4, li = lane & 15;
    const int slot = w * 4 + q;
    const int row0 = blockIdx.x * 16;
    const int node = row0 + slot;
    const int col0 = w * 32;

    // ---- phase A: edge softmax (4 heads) ----
    const int s = src[node * DEG + li];
    {
        const float4 elv = *(const float4*)(el1 + (size_t)s * 4);
        const float4 erv = *(const float4*)(er1 + (size_t)node * 4);
        float e[4] = {elv.x + erv.x, elv.y + erv.y, elv.z + erv.z, elv.w + erv.w};
#pragma unroll
        for (int h = 0; h < 4; h++) {
            float x = e[h];
            x = (x > 0.f) ? x : NEG_SLOPE * x;
            float mx = x;
#pragma unroll
            for (int d = 1; d < 16; d <<= 1) mx = fmaxf(mx, __shfl_xor(mx, d, 16));
            float ex = expf(x - mx);
            float den = ex;
#pragma unroll
            for (int d = 1; d < 16; d <<= 1) den += __shfl_xor(den, d, 16);
            s_alpha[slot][h * 16 + li] = ex / den;
        }
    }
    // ---- phase A: gather + accumulate ----
    uint4 v[16];
#pragma unroll
    for (int jj = 0; jj < 16; jj++) {
        int sj = __shfl(s, (lane & 48) | jj);
        v[jj] = *(const uint4*)(feat1 + (size_t)sj * 128 + li * 8);
    }
    float acc[8] = {0.f, 0.f, 0.f, 0.f, 0.f, 0.f, 0.f, 0.f};
    const int hrow = (li >> 2) * 16;
#pragma unroll
    for (int jj = 0; jj < 16; jj++) {
        float a = s_alpha[slot][hrow + jj];
        unsigned u0 = v[jj].x, u1 = v[jj].y, u2 = v[jj].z, u3 = v[jj].w;
        acc[0] += a * bf2f((unsigned short)(u0 & 0xFFFF));
        acc[1] += a * bf2f((unsigned short)(u0 >> 16));
        acc[2] += a * bf2f((unsigned short)(u1 & 0xFFFF));
        acc[3] += a * bf2f((unsigned short)(u1 >> 16));
        acc[4] += a * bf2f((unsigned short)(u2 & 0xFFFF));
        acc[5] += a * bf2f((unsigned short)(u2 >> 16));
        acc[6] += a * bf2f((unsigned short)(u3 & 0xFFFF));
        acc[7] += a * bf2f((unsigned short)(u3 >> 16));
    }
    const float4 bb0 = *(const float4*)(b1 + li * 8);
    const float4 bb1 = *(const float4*)(b1 + li * 8 + 4);
    float o[8];
    o[0] = fmaxf(acc[0] + bb0.x, 0.f); o[1] = fmaxf(acc[1] + bb0.y, 0.f);
    o[2] = fmaxf(acc[2] + bb0.z, 0.f); o[3] = fmaxf(acc[3] + bb0.w, 0.f);
    o[4] = fmaxf(acc[4] + bb1.x, 0.f); o[5] = fmaxf(acc[5] + bb1.y, 0.f);
    o[6] = fmaxf(acc[6] + bb1.z, 0.f); o[7] = fmaxf(acc[7] + bb1.w, 0.f);
    {
        uint4 pk;
        pk.x = pack_bf2(o[0], o[1]);
        pk.y = pack_bf2(o[2], o[3]);
        pk.z = pack_bf2(o[4], o[5]);
        pk.w = pack_bf2(o[6], o[7]);
        int jw = ((li >> 2) * 64 + (li & 3) * 16 + slot) ^ (li & 7);
        *(uint4*)&abuf[(size_t)jw * 8] = pk;
    }

    // B regs (K=128): loaded after the gather phase (peak-VGPR trim)
    bf16x8 B0[4], B1[4];
#pragma unroll
    for (int ks = 0; ks < 4; ks++) {
        B0[ks] = *(const bf16x8*)(Wt + (size_t)(col0 + li) * 128 + ks * 32 + q * 8);
        B1[ks] = *(const bf16x8*)(Wt + (size_t)(col0 + 16 + li) * 128 + ks * 32 + q * 8);
    }
    __syncthreads();

    // ---- phase B: MFMA ----
    f32x4 acc0 = {0.f, 0.f, 0.f, 0.f}, acc1 = {0.f, 0.f, 0.f, 0.f};
#pragma unroll
    for (int ks = 0; ks < 4; ks++) {
        int jr = (ks * 64 + lane) ^ ((ks * 4 + q) & 7);
        bf16x8 a = *(const bf16x8*)&abuf[(size_t)jr * 8];
        acc0 = __builtin_amdgcn_mfma_f32_16x16x32_bf16(a, B0[ks], acc0, 0, 0, 0);
        acc1 = __builtin_amdgcn_mfma_f32_16x16x32_bf16(a, B1[ks], acc1, 0, 0, 0);
    }

    // epilogue: hidden feat bf16 + el/er (1 head, cross-wave reduce)
#pragma unroll
    for (int reg = 0; reg < 4; reg++) {
        const int r = row0 + q * 4 + reg;
        feat2[(size_t)r * 128 + col0 + li]      = f2bf(acc0[reg]);
        feat2[(size_t)r * 128 + col0 + 16 + li] = f2bf(acc1[reg]);
    }
    float pe[4], pr[4];
#pragma unroll
    for (int reg = 0; reg < 4; reg++) {
        pe[reg] = acc0[reg] * alh[col0 + li] + acc1[reg] * alh[col0 + 16 + li];
        pr[reg] = acc0[reg] * arh[col0 + li] + acc1[reg] * arh[col0 + 16 + li];
    }
#pragma unroll
    for (int m = 1; m < 16; m <<= 1)
#pragma unroll
        for (int reg = 0; reg < 4; reg++) {
            pe[reg] += __shfl_xor(pe[reg], m);
            pr[reg] += __shfl_xor(pr[reg], m);
        }
    if (li == 0) {
#pragma unroll
        for (int reg = 0; reg < 4; reg++) {
            redE[w][q * 4 + reg] = pe[reg];
            redR[w][q * 4 + reg] = pr[reg];
        }
    }
    __syncthreads();
    if (tid < 16) {
        el[row0 + tid] = redE[0][tid] + redE[1][tid] + redE[2][tid] + redE[3][tid];
        er[row0 + tid] = redR[0][tid] + redR[1][tid] + redR[2][tid] + redR[3][tid];
    }
}

// ---------------- FUSED: agg2 (H=1, relu) + MFMA gemm40 --------------------------
// r15: phase B is now MFMA. Phase A packs h2 to bf16 A-fragments in an 8KB
// swizzled abuf (fusedh layout). Wave (rw=w&1, cw=w>>1): rows rw*16..+15,
// cw=0 -> frags {0,1} (cols 0..31), cw=1 -> frag 2 (cols 32..47, 40+ dead).
// B from prepped W2t[48][128] (zero-padded). el2/er2: guarded dot + shfl +
// cross-wave-pair LDS combine.
__launch_bounds__(256)
__global__ void fused40_k(const unsigned short* __restrict__ feat2,
                          const float* __restrict__ elA, const float* __restrict__ erA,
                          const int* __restrict__ src, const float* __restrict__ bh,
                          const unsigned short* __restrict__ W2t,
                          const float* __restrict__ al2, const float* __restrict__ ar2,
                          unsigned short* __restrict__ f40,
                          float* __restrict__ el2, float* __restrict__ er2)
{
    __shared__ __align__(16) unsigned short abuf[512 * 8];   // 512 slots x 16B = 8KB
    __shared__ float redE[4][16], redR[4][16];
    const int tid = threadIdx.x;
    const int w = tid >> 6, lane = tid & 63;
    const int q = lane >> 4, li = lane & 15;
    const int slot = w * 4 + q;
    const int row0 = blockIdx.x * 32;

    // ---- phase A: agg for 32 nodes, 2 rounds of 16; write bf16 A-frags ----
#pragma unroll
    for (int rnd = 0; rnd < 2; rnd++) {
        const int row = rnd * 16 + slot;
        int node = row0 + row;
        if (node > NN - 1) node = NN - 1;
        const int s = src[node * DEG + li];
        float x = elA[s] + erA[node];
        x = (x > 0.f) ? x : NEG_SLOPE * x;
        float mx = x;
#pragma unroll
        for (int d = 1; d < 16; d <<= 1) mx = fmaxf(mx, __shfl_xor(mx, d, 16));
        float ex = expf(x - mx);
        float den = ex;
#pragma unroll
        for (int d = 1; d < 16; d <<= 1) den += __shfl_xor(den, d, 16);
        const float alpha = ex / den;

        uint4 v[16];
#pragma unroll
        for (int jj = 0; jj < 16; jj++) {
            int sj = __shfl(s, (lane & 48) | jj);
            v[jj] = *(const uint4*)(feat2 + (size_t)sj * 128 + li * 8);
        }
        float acc[8] = {0.f, 0.f, 0.f, 0.f, 0.f, 0.f, 0.f, 0.f};
#pragma unroll
        for (int jj = 0; jj < 16; jj++) {
            float a = __shfl(alpha, (lane & 48) | jj);
            unsigned u0 = v[jj].x, u1 = v[jj].y, u2 = v[jj].z, u3 = v[jj].w;
            acc[0] += a * bf2f((unsigned short)(u0 & 0xFFFF));
            acc[1] += a * bf2f((unsigned short)(u0 >> 16));
            acc[2] += a * bf2f((unsigned short)(u1 & 0xFFFF));
            acc[3] += a * bf2f((unsigned short)(u1 >> 16));
            acc[4] += a * bf2f((unsigned short)(u2 & 0xFFFF));
            acc[5] += a * bf2f((unsigned short)(u2 >> 16));
            acc[6] += a * bf2f((unsigned short)(u3 & 0xFFFF));
            acc[7] += a * bf2f((unsigned short)(u3 >> 16));
        }
        const float4 bb0 = *(const float4*)(bh + li * 8);
        const float4 bb1 = *(const float4*)(bh + li * 8 + 4);
        float o[8];
        o[0] = fmaxf(acc[0] + bb0.x, 0.f); o[1] = fmaxf(acc[1] + bb0.y, 0.f);
        o[2] = fmaxf(acc[2] + bb0.z, 0.f); o[3] = fmaxf(acc[3] + bb0.w, 0.f);
        o[4] = fmaxf(acc[4] + bb1.x, 0.f); o[5] = fmaxf(acc[5] + bb1.y, 0.f);
        o[6] = fmaxf(acc[6] + bb1.z, 0.f); o[7] = fmaxf(acc[7] + bb1.w, 0.f);
        uint4 pk;
        pk.x = pack_bf2(o[0], o[1]);
        pk.y = pack_bf2(o[2], o[3]);
        pk.z = pack_bf2(o[4], o[5]);
        pk.w = pack_bf2(o[6], o[7]);
        // slot(kg=li, r=slot) in rnd's 256-slot bank, XOR-swizzled on r bits
        int jw = rnd * 256 + li * 16 + (slot ^ (li & 7));
        *(uint4*)&abuf[(size_t)jw * 8] = pk;
    }

    // B regs from W2t (after gather; cw=1 loads frag 2 twice, second unused)
    const int rw = w & 1, cw = w >> 1;
    const int cf0 = cw ? 2 : 0, cf1 = cw ? 2 : 1;
    bf16x8 Bf0[4], Bf1[4];
#pragma unroll
    for (int ks = 0; ks < 4; ks++) {
        Bf0[ks] = *(const bf16x8*)(W2t + (size_t)(cf0 * 16 + li) * 128 + ks * 32 + q * 8);
        Bf1[ks] = *(const bf16x8*)(W2t + (size_t)(cf1 * 16 + li) * 128 + ks * 32 + q * 8);
    }
    __syncthreads();

    // ---- phase B: MFMA (rows rw*16..+15) ----
    f32x4 acc0 = {0.f, 0.f, 0.f, 0.f}, acc1 = {0.f, 0.f, 0.f, 0.f};
#pragma unroll
    for (int ks = 0; ks < 4; ks++) {
        const int kg = ks * 4 + q;
        const int jr = rw * 256 + kg * 16 + (li ^ (kg & 7));
        bf16x8 a = *(const bf16x8*)&abuf[(size_t)jr * 8];
        acc0 = __builtin_amdgcn_mfma_f32_16x16x32_bf16(a, Bf0[ks], acc0, 0, 0, 0);
        acc1 = __builtin_amdgcn_mfma_f32_16x16x32_bf16(a, Bf1[ks], acc1, 0, 0, 0);
    }

    // epilogue: f40 bf16 store + el2/er2
    const int col0v = cf0 * 16 + li, col1v = cf1 * 16 + li;
#pragma unroll
    for (int reg = 0; reg < 4; reg++) {
        const int r = row0 + rw * 16 + q * 4 + reg;
        if (r < NN) {
            if (col0v < 40) f40[(size_t)r * 40 + col0v] = f2bf(acc0[reg]);
            if (cw == 0)    f40[(size_t)r * 40 + col1v] = f2bf(acc1[reg]);
        }
    }
    const float a20 = (col0v < 40) ? al2[col0v] : 0.f;
    const float r20 = (col0v < 40) ? ar2[col0v] : 0.f;
    const float a21 = (cw == 0) ? al2[col1v] : 0.f;
    const float r21 = (cw == 0) ? ar2[col1v] : 0.f;
    float pe[4], pr[4];
#pragma unroll
    for (int reg = 0; reg < 4; reg++) {
        pe[reg] = acc0[reg] * a20 + acc1[reg] * a21;
        pr[reg] = acc0[reg] * r20 + acc1[reg] * r21;
    }
#pragma unroll
    for (int m = 1; m < 16; m <<= 1)
#pragma unroll
        for (int reg = 0; reg < 4; reg++) {
            pe[reg] += __shfl_xor(pe[reg], m);
            pr[reg] += __shfl_xor(pr[reg], m);
        }
    if (li == 0) {
#pragma unroll
        for (int reg = 0; reg < 4; reg++) {
            redE[w][q * 4 + reg] = pe[reg];
            redR[w][q * 4 + reg] = pr[reg];
        }
    }
    __syncthreads();
    if (tid < 32) {
        const int rwi = tid >> 4, idx = tid & 15;
        const int r = row0 + rwi * 16 + idx;
        if (r < NN) {
            el2[r] = redE[rwi][idx] + redE[rwi + 2][idx];
            er2[r] = redR[rwi][idx] + redR[rwi + 2][idx];
        }
    }
}

// ---------------- edge softmax + aggregate 40 cols bf16 + log_softmax ------------
__launch_bounds__(256)
__global__ void agg40_ls_k(const unsigned short* __restrict__ feat, const float* __restrict__ el,
                           const float* __restrict__ er, const int* __restrict__ src,
                           const float* __restrict__ bias, float* __restrict__ out)
{
    const int tid = threadIdx.x;
    const int w = tid >> 6, lane = tid & 63;
    const int half = lane >> 5, li = lane & 31;
    const int node = blockIdx.x * 8 + w * 2 + half;

    const int s = src[node * DEG + (li & 15)];
    float e = el[s] + er[node];
    e = (e > 0.f) ? e : NEG_SLOPE * e;
    float mx = e;
#pragma unroll
    for (int d = 1; d < 16; d <<= 1) mx = fmaxf(mx, __shfl_xor(mx, d, 16));
    float ex = expf(e - mx);
    float den = ex;
#pragma unroll
    for (int d = 1; d < 16; d <<= 1) den += __shfl_xor(den, d, 16);
    const float alpha = ex / den;

    const int cli = (li < 20) ? li : 19;
    float acc0 = 0.f, acc1 = 0.f;
#pragma unroll
    for (int jj = 0; jj < DEG; jj++) {
        int sj = __shfl(s, jj, 32);
        float a = __shfl(alpha, jj, 32);
        unsigned v = *(const unsigned*)(feat + (size_t)sj * 40 + 2 * cli);
        acc0 += a * bf2f((unsigned short)(v & 0xFFFF));
        acc1 += a * bf2f((unsigned short)(v >> 16));
    }
    float v0 = acc0 + bias[2 * cli], v1 = acc1 + bias[2 * cli + 1];
    float m2 = (li < 20) ? fmaxf(v0, v1) : -INFINITY;
#pragma unroll
    for (int d = 1; d < 32; d <<= 1) m2 = fmaxf(m2, __shfl_xor(m2, d, 32));
    float pe = (li < 20) ? (expf(v0 - m2) + expf(v1 - m2)) : 0.f;
    float se = pe;
#pragma unroll
    for (int d = 1; d < 32; d <<= 1) se += __shfl_xor(se, d, 32);
    if (li < 20) {
        float ls = m2 + logf(se);
        out[(size_t)node * 40 + 2 * li]     = v0 - ls;
        out[(size_t)node * 40 + 2 * li + 1] = v1 - ls;
    }
}

extern "C" void kernel_launch(void* const* d_in, const int* in_sizes, int n_in,
                              void* d_out, int out_size, void* d_ws, size_t ws_size,
                              hipStream_t stream)
{
    const float* features = (const float*)d_in[0];
    const int*   src      = (const int*)d_in[1];
    // d_in[2] = dst: structurally repeat(arange(N),16) -> unused
    const float* W1  = (const float*)d_in[3];
    const float* al1 = (const float*)d_in[4];
    const float* ar1 = (const float*)d_in[5];
    const float* b1  = (const float*)d_in[6];
    const float* Wh  = (const float*)d_in[7];
    const float* alh = (const float*)d_in[8];
    const float* arh = (const float*)d_in[9];
    const float* bh  = (const float*)d_in[10];
    const float* W2  = (const float*)d_in[11];
    const float* al2 = (const float*)d_in[12];
    const float* ar2 = (const float*)d_in[13];
    const float* b2  = (const float*)d_in[14];
    float* out = (float*)d_out;

    float* ws = (float*)d_ws;
    unsigned short* featb  = (unsigned short*)ws;            // N*128 bf16 layer-1 feat
    unsigned short* featb2 = featb + (size_t)NN * 128;       // N*128 bf16 hidden feat
    float* el1  = (float*)(featb2 + (size_t)NN * 128);       // N*4
    float* er1  = el1 + (size_t)NN * 4;                      // N*4
    float* elA  = er1 + (size_t)NN * 4;                      // N
    float* erA  = elA + NN;                                  // N
    float* el2  = erA + NN;                                  // N
    float* er2  = el2 + NN;                                  // N
    unsigned short* f40b = (unsigned short*)(er2 + NN);      // N*40 bf16
    unsigned short* Wt1  = f40b + (size_t)NN * 40;           // 128*256 bf16
    unsigned short* Wth  = Wt1 + 128 * 256;                  // 128*128 bf16
    unsigned short* W2t  = Wth + 128 * 128;                  // 48*128 bf16 (padded)

    dim3 blk(256);
    prep_k<<<216, blk, 0, stream>>>(W1, Wt1, Wh, Wth, W2, W2t);
    gemm1_k<<<1563, blk, 0, stream>>>(features, Wt1, al1, ar1, featb, el1, er1);
    fusedh_k<<<3125, blk, 0, stream>>>(featb, el1, er1, src, b1, Wth, alh, arh,
                                       featb2, elA, erA);
    fused40_k<<<1563, blk, 0, stream>>>(featb2, elA, erA, src, bh, W2t, al2, ar2,
                                        f40b, el2, er2);
    agg40_ls_k<<<6250, blk, 0, stream>>>(f40b, el2, er2, src, b2, out);
}

// Round 16
// 113.404 us; speedup vs baseline: 1.1046x; 1.0061x over previous
//
#include <hip/hip_runtime.h>
#include <cstddef>
#include <math.h>

#define NN 50000
#define DEG 16
#define NEG_SLOPE 0.2f

typedef __attribute__((ext_vector_type(8))) short bf16x8;
typedef __attribute__((ext_vector_type(4))) float f32x4;

__device__ inline unsigned short f2bf(float x) {
    unsigned u = __float_as_uint(x);
    return (unsigned short)((u + 0x7FFF + ((u >> 16) & 1)) >> 16);
}
__device__ inline float bf2f(unsigned short u) {
    return __uint_as_float(((unsigned)u) << 16);
}
__device__ inline unsigned pack_bf2(float lo, float hi) {
    return (unsigned)f2bf(lo) | ((unsigned)f2bf(hi) << 16);
}
__device__ inline void gld_lds16f(const float* g, float* l) {
    __builtin_amdgcn_global_load_lds((const __attribute__((address_space(1))) void*)g,
                                     (__attribute__((address_space(3))) void*)l, 16, 0, 0);
}

// ---------------- prep: W1/Wh transpose -> bf16; W2t[48][128] zero-padded --------
__global__ void prep_k(const float* __restrict__ W1, unsigned short* __restrict__ Wt1,
                       const float* __restrict__ Wh, unsigned short* __restrict__ Wth,
                       const float* __restrict__ W2, unsigned short* __restrict__ W2t)
{
    const int b = blockIdx.x;
    if (b < 128) {                         // Wt1[c][k], 128x256
        int idx = b * 256 + threadIdx.x;
        int c = idx >> 8, k = idx & 255;
        Wt1[idx] = f2bf(W1[(size_t)k * 128 + c]);
    } else if (b < 192) {                  // Wth[c][k], 128x128
        int idx = (b - 128) * 256 + threadIdx.x;
        int c = idx >> 7, k = idx & 127;
        Wth[idx] = f2bf(Wh[(size_t)k * 128 + c]);
    } else {                               // W2t[c][k], 48x128 (cols 40-47 zero)
        int idx = (b - 192) * 256 + threadIdx.x;
        if (idx < 48 * 128) {
            int c = idx >> 7, k = idx & 127;
            W2t[idx] = (c < 40) ? f2bf(W2[(size_t)k * 40 + c]) : (unsigned short)0;
        }
    }
}

// ---------------- layer-1 tiled MFMA GEMM [N,256](f32 direct) x [256,128] --------
// r16: counted-vmcnt pipeline (T4-minimum). B loads (16) then stage t0 (4) then
// stage t1 (4); s_waitcnt vmcnt(4) waits B+t0 while t1 stays in flight across
// the raw barrier; vmcnt(0)+barrier BEFORE t0's epilogue stores (no store-drain).
__launch_bounds__(256)
__global__ void gemm1_k(const float* __restrict__ A,
                        const unsigned short* __restrict__ Wt,
                        const float* __restrict__ al, const float* __restrict__ ar,
                        unsigned short* __restrict__ feat,
                        float* __restrict__ el, float* __restrict__ er)
{
    constexpr int K = 256, KS = 8, TPB = 2;
    __shared__ __align__(16) float buf[2][4096];
    const int tid = threadIdx.x;
    const int w = tid >> 6, l = tid & 63;
    const int lr = l & 15, lq = l >> 4;
    const int col0 = w * 32;

    const int t0 = blockIdx.x * TPB;          // even
    const int tmax = NN / 16;                 // 3125
    if (t0 >= tmax) return;
    const bool two = (t0 + 1 < tmax);

    // B regs first: oldest vmem ops (L2-hot, short latency)
    bf16x8 B0[KS], B1[KS];
#pragma unroll
    for (int ks = 0; ks < KS; ks++) {
        B0[ks] = *(const bf16x8*)(Wt + (size_t)(col0 + lr) * K + ks * 32 + lq * 8);
        B1[ks] = *(const bf16x8*)(Wt + (size_t)(col0 + 16 + lr) * K + ks * 32 + lq * 8);
    }

    auto stage = [&](int t, int b) {
#pragma unroll
        for (int p = 0; p < 4; p++) {
            int j = tid + p * 256;
            int row = j >> 6;
            int kg = (j & 63) ^ (row & 7);
            gld_lds16f(A + (size_t)(t * 16 + row) * 256 + kg * 4, &buf[b][(size_t)j * 4]);
        }
    };
    stage(t0, 0);
    if (two) stage(t0 + 1, 1);

    // wait for B + t0 stage only; t1's 4 loads stay in flight across the barrier
    if (two) { asm volatile("s_waitcnt vmcnt(4)" ::: "memory"); }
    else     { asm volatile("s_waitcnt vmcnt(0)" ::: "memory"); }
    __builtin_amdgcn_sched_barrier(0);
    __builtin_amdgcn_s_barrier();

    auto compute = [&](int t, f32x4& a0, f32x4& a1) {
        const float* bb = buf[t & 1];
#pragma unroll
        for (int ks = 0; ks < KS; ks++) {
            const int kg0 = ks * 8 + lq * 2;
            const int s0 = lr * 64 + (kg0 ^ (lr & 7));
            const int s1 = lr * 64 + ((kg0 + 1) ^ (lr & 7));
            float4 va = *(const float4*)&bb[(size_t)s0 * 4];
            float4 vb = *(const float4*)&bb[(size_t)s1 * 4];
            bf16x8 a = {(short)f2bf(va.x), (short)f2bf(va.y),
                        (short)f2bf(va.z), (short)f2bf(va.w),
                        (short)f2bf(vb.x), (short)f2bf(vb.y),
                        (short)f2bf(vb.z), (short)f2bf(vb.w)};
            a0 = __builtin_amdgcn_mfma_f32_16x16x32_bf16(a, B0[ks], a0, 0, 0, 0);
            a1 = __builtin_amdgcn_mfma_f32_16x16x32_bf16(a, B1[ks], a1, 0, 0, 0);
        }
    };
    auto epilogue = [&](int t, const f32x4& acc0, const f32x4& acc1) {
        const int row0 = t * 16;
#pragma unroll
        for (int reg = 0; reg < 4; reg++) {
            const int r = row0 + lq * 4 + reg;
            feat[(size_t)r * 128 + col0 + lr]      = f2bf(acc0[reg]);
            feat[(size_t)r * 128 + col0 + 16 + lr] = f2bf(acc1[reg]);
        }
        float pe[4], pr[4];
#pragma unroll
        for (int reg = 0; reg < 4; reg++) {
            pe[reg] = acc0[reg] * al[col0 + lr] + acc1[reg] * al[col0 + 16 + lr];
            pr[reg] = acc0[reg] * ar[col0 + lr] + acc1[reg] * ar[col0 + 16 + lr];
        }
#pragma unroll
        for (int m = 1; m < 16; m <<= 1)
#pragma unroll
            for (int reg = 0; reg < 4; reg++) {
                pe[reg] += __shfl_xor(pe[reg], m);
                pr[reg] += __shfl_xor(pr[reg], m);
            }
        if (lr == 0) {
#pragma unroll
            for (int reg = 0; reg < 4; reg++) {
                const int r = row0 + lq * 4 + reg;
                el[r * 4 + w] = pe[reg];
                er[r * 4 + w] = pr[reg];
            }
        }
    };

    f32x4 a00 = {0.f, 0.f, 0.f, 0.f}, a01 = {0.f, 0.f, 0.f, 0.f};
    compute(t0, a00, a01);
    if (two) {
        // t1's stage must be fully landed (all waves) before reading buf[1]
        asm volatile("s_waitcnt vmcnt(0)" ::: "memory");
        __builtin_amdgcn_sched_barrier(0);
        __builtin_amdgcn_s_barrier();
    }
    epilogue(t0, a00, a01);
    if (two) {
        f32x4 a10 = {0.f, 0.f, 0.f, 0.f}, a11 = {0.f, 0.f, 0.f, 0.f};
        compute(t0 + 1, a10, a11);
        epilogue(t0 + 1, a10, a11);
    }
}

// ---------------- FUSED: agg1 (H=4, relu) + hidden MFMA GEMM ---------------------
// r16: gather loads issued BEFORE softmax (loads depend only on s) so the
// exp/div chain hides gather latency.
__launch_bounds__(256)
__global__ void fusedh_k(const unsigned short* __restrict__ feat1,
                         const float* __restrict__ el1, const float* __restrict__ er1,
                         const int* __restrict__ src, const float* __restrict__ b1,
                         const unsigned short* __restrict__ Wt,
                         const float* __restrict__ alh, const float* __restrict__ arh,
                         unsigned short* __restrict__ feat2,
                         float* __restrict__ el, float* __restrict__ er)
{
    __shared__ __align__(16) unsigned short abuf[256 * 8];   // 256 slots x 16B
    __shared__ float s_alpha[16][64];
    __shared__ float redE[4][16], redR[4][16];
    const int tid = threadIdx.x;
    const int w = tid >> 6, lane = tid & 63;
    const int q = lane >> 4, li = lane & 15;
    const int slot = w * 4 + q;
    const int row0 = blockIdx.x * 16;
    const int node = row0 + slot;
    const int col0 = w * 32;

    const int s = src[node * DEG + li];

    // gather loads first (only need s via shfl) — softmax overlaps their latency
    uint4 v[16];
#pragma unroll
    for (int jj = 0; jj < 16; jj++) {
        int sj = __shfl(s, (lane & 48) | jj);
        v[jj] = *(const uint4*)(feat1 + (size_t)sj * 128 + li * 8);
    }

    // edge softmax (4 heads)
    {
        const float4 elv = *(const float4*)(el1 + (size_t)s * 4);
        const float4 erv = *(const float4*)(er1 + (size_t)node * 4);
        float e[4] = {elv.x + erv.x, elv.y + erv.y, elv.z + erv.z, elv.w + erv.w};
#pragma unroll
        for (int h = 0; h < 4; h++) {
            float x = e[h];
            x = (x > 0.f) ? x : NEG_SLOPE * x;
            float mx = x;
#pragma unroll
            for (int d = 1; d < 16; d <<= 1) mx = fmaxf(mx, __shfl_xor(mx, d, 16));
            float ex = expf(x - mx);
            float den = ex;
#pragma unroll
            for (int d = 1; d < 16; d <<= 1) den += __shfl_xor(den, d, 16);
            s_alpha[slot][h * 16 + li] = ex / den;
        }
    }

    float acc[8] = {0.f, 0.f, 0.f, 0.f, 0.f, 0.f, 0.f, 0.f};
    const int hrow = (li >> 2) * 16;
#pragma unroll
    for (int jj = 0; jj < 16; jj++) {
        float a = s_alpha[slot][hrow + jj];
        unsigned u0 = v[jj].x, u1 = v[jj].y, u2 = v[jj].z, u3 = v[jj].w;
        acc[0] += a * bf2f((unsigned short)(u0 & 0xFFFF));
        acc[1] += a * bf2f((unsigned short)(u0 >> 16));
        acc[2] += a * bf2f((unsigned short)(u1 & 0xFFFF));
        acc[3] += a * bf2f((unsigned short)(u1 >> 16));
        acc[4] += a * bf2f((unsigned short)(u2 & 0xFFFF));
        acc[5] += a * bf2f((unsigned short)(u2 >> 16));
        acc[6] += a * bf2f((unsigned short)(u3 & 0xFFFF));
        acc[7] += a * bf2f((unsigned short)(u3 >> 16));
    }
    const float4 bb0 = *(const float4*)(b1 + li * 8);
    const float4 bb1 = *(const float4*)(b1 + li * 8 + 4);
    float o[8];
    o[0] = fmaxf(acc[0] + bb0.x, 0.f); o[1] = fmaxf(acc[1] + bb0.y, 0.f);
    o[2] = fmaxf(acc[2] + bb0.z, 0.f); o[3] = fmaxf(acc[3] + bb0.w, 0.f);
    o[4] = fmaxf(acc[4] + bb1.x, 0.f); o[5] = fmaxf(acc[5] + bb1.y, 0.f);
    o[6] = fmaxf(acc[6] + bb1.z, 0.f); o[7] = fmaxf(acc[7] + bb1.w, 0.f);
    {
        uint4 pk;
        pk.x = pack_bf2(o[0], o[1]);
        pk.y = pack_bf2(o[2], o[3]);
        pk.z = pack_bf2(o[4], o[5]);
        pk.w = pack_bf2(o[6], o[7]);
        int jw = ((li >> 2) * 64 + (li & 3) * 16 + slot) ^ (li & 7);
        *(uint4*)&abuf[(size_t)jw * 8] = pk;
    }

    // B regs (K=128): loaded after the gather phase (peak-VGPR trim)
    bf16x8 B0[4], B1[4];
#pragma unroll
    for (int ks = 0; ks < 4; ks++) {
        B0[ks] = *(const bf16x8*)(Wt + (size_t)(col0 + li) * 128 + ks * 32 + q * 8);
        B1[ks] = *(const bf16x8*)(Wt + (size_t)(col0 + 16 + li) * 128 + ks * 32 + q * 8);
    }
    __syncthreads();

    // ---- phase B: MFMA ----
    f32x4 acc0 = {0.f, 0.f, 0.f, 0.f}, acc1 = {0.f, 0.f, 0.f, 0.f};
#pragma unroll
    for (int ks = 0; ks < 4; ks++) {
        int jr = (ks * 64 + lane) ^ ((ks * 4 + q) & 7);
        bf16x8 a = *(const bf16x8*)&abuf[(size_t)jr * 8];
        acc0 = __builtin_amdgcn_mfma_f32_16x16x32_bf16(a, B0[ks], acc0, 0, 0, 0);
        acc1 = __builtin_amdgcn_mfma_f32_16x16x32_bf16(a, B1[ks], acc1, 0, 0, 0);
    }

    // epilogue: hidden feat bf16 + el/er (1 head, cross-wave reduce)
#pragma unroll
    for (int reg = 0; reg < 4; reg++) {
        const int r = row0 + q * 4 + reg;
        feat2[(size_t)r * 128 + col0 + li]      = f2bf(acc0[reg]);
        feat2[(size_t)r * 128 + col0 + 16 + li] = f2bf(acc1[reg]);
    }
    float pe[4], pr[4];
#pragma unroll
    for (int reg = 0; reg < 4; reg++) {
        pe[reg] = acc0[reg] * alh[col0 + li] + acc1[reg] * alh[col0 + 16 + li];
        pr[reg] = acc0[reg] * arh[col0 + li] + acc1[reg] * arh[col0 + 16 + li];
    }
#pragma unroll
    for (int m = 1; m < 16; m <<= 1)
#pragma unroll
        for (int reg = 0; reg < 4; reg++) {
            pe[reg] += __shfl_xor(pe[reg], m);
            pr[reg] += __shfl_xor(pr[reg], m);
        }
    if (li == 0) {
#pragma unroll
        for (int reg = 0; reg < 4; reg++) {
            redE[w][q * 4 + reg] = pe[reg];
            redR[w][q * 4 + reg] = pr[reg];
        }
    }
    __syncthreads();
    if (tid < 16) {
        el[row0 + tid] = redE[0][tid] + redE[1][tid] + redE[2][tid] + redE[3][tid];
        er[row0 + tid] = redR[0][tid] + redR[1][tid] + redR[2][tid] + redR[3][tid];
    }
}

// ---------------- FUSED: agg2 (H=1, relu) + MFMA gemm40 --------------------------
// (r15 structure; r16: gather loads issued before softmax in each round)
__launch_bounds__(256)
__global__ void fused40_k(const unsigned short* __restrict__ feat2,
                          const float* __restrict__ elA, const float* __restrict__ erA,
                          const int* __restrict__ src, const float* __restrict__ bh,
                          const unsigned short* __restrict__ W2t,
                          const float* __restrict__ al2, const float* __restrict__ ar2,
                          unsigned short* __restrict__ f40,
                          float* __restrict__ el2, float* __restrict__ er2)
{
    __shared__ __align__(16) unsigned short abuf[512 * 8];   // 512 slots x 16B = 8KB
    __shared__ float redE[4][16], redR[4][16];
    const int tid = threadIdx.x;
    const int w = tid >> 6, lane = tid & 63;
    const int q = lane >> 4, li = lane & 15;
    const int slot = w * 4 + q;
    const int row0 = blockIdx.x * 32;

    // ---- phase A: agg for 32 nodes, 2 rounds of 16; write bf16 A-frags ----
#pragma unroll
    for (int rnd = 0; rnd < 2; rnd++) {
        const int row = rnd * 16 + slot;
        int node = row0 + row;
        if (node > NN - 1) node = NN - 1;
        const int s = src[node * DEG + li];

        uint4 v[16];
#pragma unroll
        for (int jj = 0; jj < 16; jj++) {
            int sj = __shfl(s, (lane & 48) | jj);
            v[jj] = *(const uint4*)(feat2 + (size_t)sj * 128 + li * 8);
        }

        float x = elA[s] + erA[node];
        x = (x > 0.f) ? x : NEG_SLOPE * x;
        float mx = x;
#pragma unroll
        for (int d = 1; d < 16; d <<= 1) mx = fmaxf(mx, __shfl_xor(mx, d, 16));
        float ex = expf(x - mx);
        float den = ex;
#pragma unroll
        for (int d = 1; d < 16; d <<= 1) den += __shfl_xor(den, d, 16);
        const float alpha = ex / den;

        float acc[8] = {0.f, 0.f, 0.f, 0.f, 0.f, 0.f, 0.f, 0.f};
#pragma unroll
        for (int jj = 0; jj < 16; jj++) {
            float a = __shfl(alpha, (lane & 48) | jj);
            unsigned u0 = v[jj].x, u1 = v[jj].y, u2 = v[jj].z, u3 = v[jj].w;
            acc[0] += a * bf2f((unsigned short)(u0 & 0xFFFF));
            acc[1] += a * bf2f((unsigned short)(u0 >> 16));
            acc[2] += a * bf2f((unsigned short)(u1 & 0xFFFF));
            acc[3] += a * bf2f((unsigned short)(u1 >> 16));
            acc[4] += a * bf2f((unsigned short)(u2 & 0xFFFF));
            acc[5] += a * bf2f((unsigned short)(u2 >> 16));
            acc[6] += a * bf2f((unsigned short)(u3 & 0xFFFF));
            acc[7] += a * bf2f((unsigned short)(u3 >> 16));
        }
        const float4 bb0 = *(const float4*)(bh + li * 8);
        const float4 bb1 = *(const float4*)(bh + li * 8 + 4);
        float o[8];
        o[0] = fmaxf(acc[0] + bb0.x, 0.f); o[1] = fmaxf(acc[1] + bb0.y, 0.f);
        o[2] = fmaxf(acc[2] + bb0.z, 0.f); o[3] = fmaxf(acc[3] + bb0.w, 0.f);
        o[4] = fmaxf(acc[4] + bb1.x, 0.f); o[5] = fmaxf(acc[5] + bb1.y, 0.f);
        o[6] = fmaxf(acc[6] + bb1.z, 0.f); o[7] = fmaxf(acc[7] + bb1.w, 0.f);
        uint4 pk;
        pk.x = pack_bf2(o[0], o[1]);
        pk.y = pack_bf2(o[2], o[3]);
        pk.z = pack_bf2(o[4], o[5]);
        pk.w = pack_bf2(o[6], o[7]);
        int jw = rnd * 256 + li * 16 + (slot ^ (li & 7));
        *(uint4*)&abuf[(size_t)jw * 8] = pk;
    }

    // B regs from W2t (after gather; cw=1 loads frag 2 twice, second unused)
    const int rw = w & 1, cw = w >> 1;
    const int cf0 = cw ? 2 : 0, cf1 = cw ? 2 : 1;
    bf16x8 Bf0[4], Bf1[4];
#pragma unroll
    for (int ks = 0; ks < 4; ks++) {
        Bf0[ks] = *(const bf16x8*)(W2t + (size_t)(cf0 * 16 + li) * 128 + ks * 32 + q * 8);
        Bf1[ks] = *(const bf16x8*)(W2t + (size_t)(cf1 * 16 + li) * 128 + ks * 32 + q * 8);
    }
    __syncthreads();

    // ---- phase B: MFMA (rows rw*16..+15) ----
    f32x4 acc0 = {0.f, 0.f, 0.f, 0.f}, acc1 = {0.f, 0.f, 0.f, 0.f};
#pragma unroll
    for (int ks = 0; ks < 4; ks++) {
        const int kg = ks * 4 + q;
        const int jr = rw * 256 + kg * 16 + (li ^ (kg & 7));
        bf16x8 a = *(const bf16x8*)&abuf[(size_t)jr * 8];
        acc0 = __builtin_amdgcn_mfma_f32_16x16x32_bf16(a, Bf0[ks], acc0, 0, 0, 0);
        acc1 = __builtin_amdgcn_mfma_f32_16x16x32_bf16(a, Bf1[ks], acc1, 0, 0, 0);
    }

    // epilogue: f40 bf16 store + el2/er2
    const int col0v = cf0 * 16 + li, col1v = cf1 * 16 + li;
#pragma unroll
    for (int reg = 0; reg < 4; reg++) {
        const int r = row0 + rw * 16 + q * 4 + reg;
        if (r < NN) {
            if (col0v < 40) f40[(size_t)r * 40 + col0v] = f2bf(acc0[reg]);
            if (cw == 0)    f40[(size_t)r * 40 + col1v] = f2bf(acc1[reg]);
        }
    }
    const float a20 = (col0v < 40) ? al2[col0v] : 0.f;
    const float r20 = (col0v < 40) ? ar2[col0v] : 0.f;
    const float a21 = (cw == 0) ? al2[col1v] : 0.f;
    const float r21 = (cw == 0) ? ar2[col1v] : 0.f;
    float pe[4], pr[4];
#pragma unroll
    for (int reg = 0; reg < 4; reg++) {
        pe[reg] = acc0[reg] * a20 + acc1[reg] * a21;
        pr[reg] = acc0[reg] * r20 + acc1[reg] * r21;
    }
#pragma unroll
    for (int m = 1; m < 16; m <<= 1)
#pragma unroll
        for (int reg = 0; reg < 4; reg++) {
            pe[reg] += __shfl_xor(pe[reg], m);
            pr[reg] += __shfl_xor(pr[reg], m);
        }
    if (li == 0) {
#pragma unroll
        for (int reg = 0; reg < 4; reg++) {
            redE[w][q * 4 + reg] = pe[reg];
            redR[w][q * 4 + reg] = pr[reg];
        }
    }
    __syncthreads();
    if (tid < 32) {
        const int rwi = tid >> 4, idx = tid & 15;
        const int r = row0 + rwi * 16 + idx;
        if (r < NN) {
            el2[r] = redE[rwi][idx] + redE[rwi + 2][idx];
            er2[r] = redR[rwi][idx] + redR[rwi + 2][idx];
        }
    }
}

// ---------------- edge softmax + aggregate 40 cols bf16 + log_softmax ------------
__launch_bounds__(256)
__global__ void agg40_ls_k(const unsigned short* __restrict__ feat, const float* __restrict__ el,
                           const float* __restrict__ er, const int* __restrict__ src,
                           const float* __restrict__ bias, float* __restrict__ out)
{
    const int tid = threadIdx.x;
    const int w = tid >> 6, lane = tid & 63;
    const int half = lane >> 5, li = lane & 31;
    const int node = blockIdx.x * 8 + w * 2 + half;

    const int s = src[node * DEG + (li & 15)];
    float e = el[s] + er[node];
    e = (e > 0.f) ? e : NEG_SLOPE * e;
    float mx = e;
#pragma unroll
    for (int d = 1; d < 16; d <<= 1) mx = fmaxf(mx, __shfl_xor(mx, d, 16));
    float ex = expf(e - mx);
    float den = ex;
#pragma unroll
    for (int d = 1; d < 16; d <<= 1) den += __shfl_xor(den, d, 16);
    const float alpha = ex / den;

    const int cli = (li < 20) ? li : 19;
    float acc0 = 0.f, acc1 = 0.f;
#pragma unroll
    for (int jj = 0; jj < DEG; jj++) {
        int sj = __shfl(s, jj, 32);
        float a = __shfl(alpha, jj, 32);
        unsigned v = *(const unsigned*)(feat + (size_t)sj * 40 + 2 * cli);
        acc0 += a * bf2f((unsigned short)(v & 0xFFFF));
        acc1 += a * bf2f((unsigned short)(v >> 16));
    }
    float v0 = acc0 + bias[2 * cli], v1 = acc1 + bias[2 * cli + 1];
    float m2 = (li < 20) ? fmaxf(v0, v1) : -INFINITY;
#pragma unroll
    for (int d = 1; d < 32; d <<= 1) m2 = fmaxf(m2, __shfl_xor(m2, d, 32));
    float pe = (li < 20) ? (expf(v0 - m2) + expf(v1 - m2)) : 0.f;
    float se = pe;
#pragma unroll
    for (int d = 1; d < 32; d <<= 1) se += __shfl_xor(se, d, 32);
    if (li < 20) {
        float ls = m2 + logf(se);
        out[(size_t)node * 40 + 2 * li]     = v0 - ls;
        out[(size_t)node * 40 + 2 * li + 1] = v1 - ls;
    }
}

extern "C" void kernel_launch(void* const* d_in, const int* in_sizes, int n_in,
                              void* d_out, int out_size, void* d_ws, size_t ws_size,
                              hipStream_t stream)
{
    const float* features = (const float*)d_in[0];
    const int*   src      = (const int*)d_in[1];
    // d_in[2] = dst: structurally repeat(arange(N),16) -> unused
    const float* W1  = (const float*)d_in[3];
    const float* al1 = (const float*)d_in[4];
    const float* ar1 = (const float*)d_in[5];
    const float* b1  = (const float*)d_in[6];
    const float* Wh  = (const float*)d_in[7];
    const float* alh = (const float*)d_in[8];
    const float* arh = (const float*)d_in[9];
    const float* bh  = (const float*)d_in[10];
    const float* W2  = (const float*)d_in[11];
    const float* al2 = (const float*)d_in[12];
    const float* ar2 = (const float*)d_in[13];
    const float* b2  = (const float*)d_in[14];
    float* out = (float*)d_out;

    float* ws = (float*)d_ws;
    unsigned short* featb  = (unsigned short*)ws;            // N*128 bf16 layer-1 feat
    unsigned short* featb2 = featb + (size_t)NN * 128;       // N*128 bf16 hidden feat
    float* el1  = (float*)(featb2 + (size_t)NN * 128);       // N*4
    float* er1  = el1 + (size_t)NN * 4;                      // N*4
    float* elA  = er1 + (size_t)NN * 4;                      // N
    float* erA  = elA + NN;                                  // N
    float* el2  = erA + NN;                                  // N
    float* er2  = el2 + NN;                                  // N
    unsigned short* f40b = (unsigned short*)(er2 + NN);      // N*40 bf16
    unsigned short* Wt1  = f40b + (size_t)NN * 40;           // 128*256 bf16
    unsigned short* Wth  = Wt1 + 128 * 256;                  // 128*128 bf16
    unsigned short* W2t  = Wth + 128 * 128;                  // 48*128 bf16 (padded)

    dim3 blk(256);
    prep_k<<<216, blk, 0, stream>>>(W1, Wt1, Wh, Wth, W2, W2t);
    gemm1_k<<<1563, blk, 0, stream>>>(features, Wt1, al1, ar1, featb, el1, er1);
    fusedh_k<<<3125, blk, 0, stream>>>(featb, el1, er1, src, b1, Wth, alh, arh,
                                       featb2, elA, erA);
    fused40_k<<<1563, blk, 0, stream>>>(featb2, elA, erA, src, bh, W2t, al2, ar2,
                                        f40b, el2, er2);
    agg40_ls_k<<<6250, blk, 0, stream>>>(f40b, el2, er2, src, b2, out);
}